// Round 5
// baseline (486.577 us; speedup 1.0000x reference)
//
#include <hip/hip_runtime.h>

using bf16x8 = __attribute__((ext_vector_type(8))) short;
using f32x4  = __attribute__((ext_vector_type(4))) float;

#define B_  2
#define T_  2048
#define C_  2048
#define H_  16
#define KV_ 4
#define D_  128

__device__ __forceinline__ unsigned short f2b(float f) {
  union { float f; unsigned int u; } v; v.f = f;
  unsigned int r = v.u + 0x7fffu + ((v.u >> 16) & 1u);   // RTNE
  return (unsigned short)(r >> 16);
}
__device__ __forceinline__ float b2f(unsigned short u) {
  union { unsigned int u; float f; } v; v.u = ((unsigned int)u) << 16;
  return v.f;
}
// async global->LDS, 16B per lane; LDS dest must be lane-contiguous (wave base + lane*16)
__device__ __forceinline__ void gld_lds16(const void* g, void* l) {
  __builtin_amdgcn_global_load_lds(
      (__attribute__((address_space(1))) void*)g,
      (__attribute__((address_space(3))) void*)l, 16, 0, 0);
}

// ---------------- elementwise cast x -> bf16 ----------------
__global__ void cast_bf16_k(const float* __restrict__ in, unsigned short* __restrict__ out) {
  int i = blockIdx.x * 256 + threadIdx.x;
  float4 f = ((const float4*)in)[i];
  ushort4 u; u.x = f2b(f.x); u.y = f2b(f.y); u.z = f2b(f.z); u.w = f2b(f.w);
  ((ushort4*)out)[i] = u;
}

// ---------------- transpose-cast W (K x N fp32) -> Wt (N x K bf16) ----------------
__global__ void wtrans(const float* __restrict__ W, unsigned short* __restrict__ Wt,
                       int K, int N) {
  __shared__ float s[32][33];
  int n0 = blockIdx.x * 32, k0 = blockIdx.y * 32;
  int tx = threadIdx.x, ty = threadIdx.y;
  #pragma unroll
  for (int yy = 0; yy < 32; yy += 8)
    s[ty + yy][tx] = W[(size_t)(k0 + ty + yy) * N + n0 + tx];
  __syncthreads();
  #pragma unroll
  for (int yy = 0; yy < 32; yy += 8)
    Wt[(size_t)(n0 + ty + yy) * K + k0 + tx] = f2b(s[tx][ty + yy]);
}

// ---------------- m97-style bf16 MFMA GEMM tile: C = A(MxK) * Bt(NxK)^T ----------------
template <bool OUT_BF16>
__device__ __forceinline__ void gemm_tile(
    const unsigned short* __restrict__ A, const unsigned short* __restrict__ Bt,
    void* __restrict__ Cv, int K, int ldc, int m0, int n0b, int n0c,
    unsigned short* sA, unsigned short* sB)
{
  const int tid  = threadIdx.x;
  const int lane = tid & 63, w = tid >> 6;
  const int quad = lane >> 4, l16 = lane & 15;
  const int wm = (w >> 1) * 64, wn = (w & 1) * 64;

  f32x4 acc[4][4] = {};

  const unsigned short* Abase = A  + (size_t)m0  * K;
  const unsigned short* Bbase = Bt + (size_t)n0b * K;

  for (int k0 = 0; k0 < K; k0 += 32) {
    #pragma unroll
    for (int r = 0; r < 2; ++r) {                   // 128x32 bf16 tile = 512 chunks of 16B
      int c = tid + r * 256;
      int row = c >> 2, col = (c & 3) * 8;
      gld_lds16(Abase + (size_t)row * K + k0 + col, sA + c * 8);
      gld_lds16(Bbase + (size_t)row * K + k0 + col, sB + c * 8);
    }
    __syncthreads();                                // drains vmcnt, LDS visible
    bf16x8 af[4], bfr[4];
    #pragma unroll
    for (int i = 0; i < 4; ++i)
      af[i]  = *(const bf16x8*)(sA + (wm + i * 16 + l16) * 32 + quad * 8);
    #pragma unroll
    for (int j = 0; j < 4; ++j)
      bfr[j] = *(const bf16x8*)(sB + (wn + j * 16 + l16) * 32 + quad * 8);
    #pragma unroll
    for (int i = 0; i < 4; ++i)
      #pragma unroll
      for (int j = 0; j < 4; ++j)
        acc[i][j] = __builtin_amdgcn_mfma_f32_16x16x32_bf16(af[i], bfr[j], acc[i][j], 0, 0, 0);
    __syncthreads();                                // all waves done reading before overwrite
  }
  #pragma unroll
  for (int i = 0; i < 4; ++i) {
    #pragma unroll
    for (int r = 0; r < 4; ++r) {
      int row = m0 + wm + i * 16 + quad * 4 + r;    // C/D: row = quad*4+reg, col = lane&15
      #pragma unroll
      for (int j = 0; j < 4; ++j) {
        int col = n0c + wn + j * 16 + l16;
        float v = acc[i][j][r];
        if (OUT_BF16) ((unsigned short*)Cv)[(size_t)row * ldc + col] = f2b(v);
        else          ((float*)Cv)[(size_t)row * ldc + col] = v;
      }
    }
  }
}

// fused QKV projection: 24 n-tiles (16 Q, 4 K, 4 V) x 32 m-tiles
__global__ void qkv_gemm(const unsigned short* __restrict__ xb,
                         const unsigned short* __restrict__ Wqt,
                         const unsigned short* __restrict__ Wkt,
                         const unsigned short* __restrict__ Wvt,
                         unsigned short* q, unsigned short* k, unsigned short* v) {
  __shared__ unsigned short sA[128 * 32], sB[128 * 32];
  int nt = blockIdx.x, mt = blockIdx.y;
  const unsigned short* Bt; unsigned short* C; int n0, ldc;
  if (nt < 16)      { Bt = Wqt; C = q; n0 = nt * 128;        ldc = H_ * D_;  }
  else if (nt < 20) { Bt = Wkt; C = k; n0 = (nt - 16) * 128; ldc = KV_ * D_; }
  else              { Bt = Wvt; C = v; n0 = (nt - 20) * 128; ldc = KV_ * D_; }
  gemm_tile<true>(xb, Bt, C, C_, ldc, mt * 128, n0, n0, sA, sB);
}

__global__ void out_gemm(const unsigned short* __restrict__ yb,
                         const unsigned short* __restrict__ Wot,
                         float* __restrict__ out) {
  __shared__ unsigned short sA[128 * 32], sB[128 * 32];
  gemm_tile<false>(yb, Wot, out, C_, C_, blockIdx.y * 128, blockIdx.x * 128, blockIdx.x * 128,
                   sA, sB);
}

// ---------------- RoPE + RMSNorm -> MFMA-fragment-order output ----------------
// per (b,head): [t16 (128 tiles)][f = d>>3 (16)][t&15 (16)][d&7 (8)]  (tile = 2048 shorts)
template <int NH>
__global__ void ropenorm(const unsigned short* __restrict__ in,
                         const float* __restrict__ cs, const float* __restrict__ sn,
                         unsigned short* __restrict__ out, float oscale) {
  int row  = blockIdx.x * 4 + (threadIdx.x >> 6);
  int lane = threadIdx.x & 63;
  int head = row % NH;
  int t = (row / NH) & (T_ - 1);
  int b = row / (NH * T_);
  const unsigned short* p = in + (size_t)row * D_;
  float t1 = b2f(p[lane]), t2 = b2f(p[lane + 64]);
  float c = cs[t * 64 + lane], s = sn[t * 64 + lane];
  float o1 = t1 * c + t2 * s;
  float o2 = t2 * c - t1 * s;
  float ss = o1 * o1 + o2 * o2;
  #pragma unroll
  for (int off = 32; off > 0; off >>= 1) ss += __shfl_xor(ss, off, 64);
  float r = rsqrtf(ss * (1.0f / 128.0f) + 1.1920929e-07f) * oscale;
  size_t base = ((size_t)((b * NH + head) * 128 + (t >> 4))) * 2048 + (size_t)(t & 15) * 8;
  out[base + (size_t)(lane >> 3) * 128 + (lane & 7)]       = f2b(o1 * r);
  out[base + (size_t)(8 + (lane >> 3)) * 128 + (lane & 7)] = f2b(o2 * r);
}

// ---------------- V repack: (B,T,KV,D) bf16 -> fragment order for PV B-operand ---------
// per (b,kv): [it (32 tiles of 64 t)][dt = d>>4 (8)][f = (t&63)>>3 (8)][d&15 (16)][t&7 (8)]
__global__ void vfrag_k(const unsigned short* __restrict__ v, unsigned short* __restrict__ vf) {
  int it = blockIdx.x;
  int b = blockIdx.y >> 2, kv = blockIdx.y & 3;
  int d = threadIdx.x, ty = threadIdx.y;
  int t0 = it * 64;
  size_t obase = ((size_t)((b * KV_ + kv) * 32 + it)) * 8192
               + (size_t)(d >> 4) * 1024 + (size_t)(d & 15) * 8;
  #pragma unroll
  for (int tcg = 0; tcg < 4; ++tcg) {
    int tc = ty * 4 + tcg;                   // f chunk 0..7
    unsigned short val[8];
    #pragma unroll
    for (int e = 0; e < 8; ++e)              // coalesced: 128 lanes contiguous in d
      val[e] = v[(((size_t)(b * T_) + t0 + tc * 8 + e) * KV_ + kv) * D_ + d];
    ushort4 u0 = {val[0], val[1], val[2], val[3]};
    ushort4 u1 = {val[4], val[5], val[6], val[7]};
    *(ushort4*)(vf + obase + (size_t)tc * 128)     = u0;
    *(ushort4*)(vf + obase + (size_t)tc * 128 + 4) = u1;
  }
}

// ---------------- flash attention v5: split-K segments for occupancy -------------------
// One wave per block, 32 Q rows. qt<32: single segment (<=16 iters), direct write.
// qt>=32: k-range split into segments of 8 KV-tiles; each writes unnormalized bf16
// partial O + per-row (m,l); attn_merge combines. Grid (144,32) = 4608 waves.
__global__ __launch_bounds__(64, 4) void attn_kernel(
    const unsigned short* __restrict__ qf, const unsigned short* __restrict__ kf,
    const unsigned short* __restrict__ vf, unsigned short* __restrict__ yb,
    unsigned short* __restrict__ pO, float* __restrict__ pml) {
  __shared__ unsigned short sP[32 * 72];       // 4.6 KB private P slice (stride 72)

  const int x = (int)blockIdx.x;
  int qt, it0, it1, pslot; bool direct;
  if (x < 32) {                                // qt 31..0, heavy first
    qt = 31 - x; direct = true; pslot = 0;
    it0 = 0; it1 = (qt >> 1) + 1;
  } else if (x < 80) {                         // qt 32..47, 3 segs each
    int e = x - 32; int j = e / 3; int seg = e - j * 3;
    qt = 32 + j; direct = false; pslot = e;
    it0 = seg * 8; int nt = (qt >> 1) + 1; it1 = it0 + 8 < nt ? it0 + 8 : nt;
  } else {                                     // qt 48..63, 4 segs each
    int e = x - 80; int j = e >> 2; int seg = e & 3;
    qt = 48 + j; direct = false; pslot = 48 + e;
    it0 = seg * 8; int nt = (qt >> 1) + 1; it1 = it0 + 8 < nt ? it0 + 8 : nt;
  }
  const int ntile = (qt >> 1) + 1;             // global diagonal tile index + 1
  const int q0 = qt * 32;
  const int bh = blockIdx.y;
  const int b = bh >> 4, h = bh & 15, kv = h >> 2;

  const int lane = threadIdx.x & 63;
  const int quad = lane >> 4, l16 = lane & 15;

  const unsigned short* Qf = qf + ((size_t)(b * H_ + h) * 128 + qt * 2) * 2048;
  const unsigned short* Kf = kf + (size_t)(b * KV_ + kv) * 128 * 2048;
  const unsigned short* Vf = vf + (size_t)(b * KV_ + kv) * 32 * 8192;

  // persistent Q fragments (B-operand: n = q row, k = head dim), coalesced frag-order load
  bf16x8 bq[2][4];
  #pragma unroll
  for (int i = 0; i < 2; ++i)
    #pragma unroll
    for (int kk = 0; kk < 4; ++kk)
      bq[i][kk] = *(const bf16x8*)(Qf + (size_t)i * 2048 + (kk * 4 + quad) * 128 + l16 * 8);

  float m_i[2] = {-INFINITY, -INFINITY}, l_i[2] = {0.f, 0.f};
  f32x4 o[2][8] = {};                          // rows q (C-layout), cols d

  for (int it = it0; it < it1; ++it) {
    const int t0 = it * 64;
    const unsigned short* Kt = Kf + (size_t)(it * 4) * 2048;
    const unsigned short* Vt = Vf + (size_t)it * 8192;

    // S^T = K Q^T : 64 k rows (4 tiles) x 32 q cols (2 tiles)
    f32x4 sc[4][2] = {};
    #pragma unroll
    for (int kk = 0; kk < 4; ++kk) {
      bf16x8 ak[4];
      #pragma unroll
      for (int jt = 0; jt < 4; ++jt)
        ak[jt] = *(const bf16x8*)(Kt + (size_t)jt * 2048 + (kk * 4 + quad) * 128 + l16 * 8);
      #pragma unroll
      for (int jt = 0; jt < 4; ++jt)
        #pragma unroll
        for (int i = 0; i < 2; ++i)
          sc[jt][i] = __builtin_amdgcn_mfma_f32_16x16x32_bf16(ak[jt], bq[i][kk], sc[jt][i], 0, 0, 0);
    }

    if (it == ntile - 1) {                     // causal mask only on the diagonal tile
      #pragma unroll
      for (int jt = 0; jt < 4; ++jt) {
        int kg = t0 + jt * 16 + quad * 4;
        #pragma unroll
        for (int i = 0; i < 2; ++i) {
          int qg = q0 + i * 16 + l16;
          #pragma unroll
          for (int r = 0; r < 4; ++r)
            if (kg + r > qg) sc[jt][i][r] = -3.0e38f;
        }
      }
    }

    // online softmax per q column; stats replicated across quads (2 shuffles each)
    #pragma unroll
    for (int i = 0; i < 2; ++i) {
      float mx = -3.0e38f;
      #pragma unroll
      for (int jt = 0; jt < 4; ++jt)
        #pragma unroll
        for (int r = 0; r < 4; ++r) mx = fmaxf(mx, sc[jt][i][r]);
      mx = fmaxf(mx, __shfl_xor(mx, 16, 64));
      mx = fmaxf(mx, __shfl_xor(mx, 32, 64));
      float mnew = fmaxf(m_i[i], mx);
      float a = __expf(m_i[i] - mnew);
      float rs = 0.f;
      #pragma unroll
      for (int jt = 0; jt < 4; ++jt)
        #pragma unroll
        for (int r = 0; r < 4; ++r) {
          float p = __expf(sc[jt][i][r] - mnew);
          sc[jt][i][r] = p; rs += p;
        }
      rs += __shfl_xor(rs, 16, 64);
      rs += __shfl_xor(rs, 32, 64);
      m_i[i] = mnew; l_i[i] = l_i[i] * a + rs;
      float ar[4];
      #pragma unroll
      for (int r = 0; r < 4; ++r) ar[r] = __shfl(a, quad * 4 + r, 64);
      #pragma unroll
      for (int j = 0; j < 8; ++j)
        #pragma unroll
        for (int r = 0; r < 4; ++r) o[i][j][r] *= ar[r];
    }

    // P^T (C-layout) -> private LDS row-major P [q32][k64]
    #pragma unroll
    for (int i = 0; i < 2; ++i)
      #pragma unroll
      for (int jt = 0; jt < 4; ++jt) {
        ushort4 u;
        u.x = f2b(sc[jt][i][0]); u.y = f2b(sc[jt][i][1]);
        u.z = f2b(sc[jt][i][2]); u.w = f2b(sc[jt][i][3]);
        *(ushort4*)(sP + (i * 16 + l16) * 72 + jt * 16 + quad * 4) = u;
      }

    // O += P V : A from private LDS, B direct from frag-order global (coalesced)
    #pragma unroll
    for (int kk2 = 0; kk2 < 2; ++kk2) {
      bf16x8 ap[2], bv[8];
      #pragma unroll
      for (int i = 0; i < 2; ++i)
        ap[i] = *(const bf16x8*)(sP + (i * 16 + l16) * 72 + kk2 * 32 + quad * 8);
      #pragma unroll
      for (int j = 0; j < 8; ++j)
        bv[j] = *(const bf16x8*)(Vt + (size_t)j * 1024 + (kk2 * 4 + quad) * 128 + l16 * 8);
      #pragma unroll
      for (int i = 0; i < 2; ++i)
        #pragma unroll
        for (int j = 0; j < 8; ++j)
          o[i][j] = __builtin_amdgcn_mfma_f32_16x16x32_bf16(ap[i], bv[j], o[i][j], 0, 0, 0);
    }
  }

  if (direct) {
    #pragma unroll
    for (int i = 0; i < 2; ++i) {
      float linv = 1.0f / l_i[i];
      float lr[4];
      #pragma unroll
      for (int r = 0; r < 4; ++r) lr[r] = __shfl(linv, quad * 4 + r, 64);
      #pragma unroll
      for (int r = 0; r < 4; ++r) {
        int tg = q0 + i * 16 + quad * 4 + r;
        unsigned short* yr = yb + (((size_t)(b * T_ + tg)) * H_ + h) * D_;
        #pragma unroll
        for (int j = 0; j < 8; ++j)
          yr[j * 16 + l16] = f2b(o[i][j][r] * lr[r]);
      }
    }
  } else {
    const int p = bh * 112 + pslot;
    unsigned short* Ob = pO + (size_t)p * 4096;
    #pragma unroll
    for (int i = 0; i < 2; ++i)
      #pragma unroll
      for (int r = 0; r < 4; ++r) {
        int row = i * 16 + quad * 4 + r;
        #pragma unroll
        for (int j = 0; j < 8; ++j)
          Ob[row * 128 + j * 16 + l16] = f2b(o[i][j][r]);
      }
    if (quad == 0) {
      #pragma unroll
      for (int i = 0; i < 2; ++i) {
        pml[(size_t)p * 64 + i * 16 + l16]      = m_i[i];
        pml[(size_t)p * 64 + 32 + i * 16 + l16] = l_i[i];
      }
    }
  }
}

// ---------------- merge split-K partials: Y = (sum_s O_s e^{m_s-M}) / L ----------------
__global__ void attn_merge(const unsigned short* __restrict__ pO,
                           const float* __restrict__ pml,
                           unsigned short* __restrict__ yb) {
  int x = blockIdx.x;                          // 1024 = 32 bh x 32 qt (qt 32..63)
  int bh = x >> 5, qi = x & 31;
  int qt = 32 + qi;
  int b = bh >> 4, h = bh & 15;
  int nseg = qt < 48 ? 3 : 4;
  int base = bh * 112 + (qt < 48 ? (qt - 32) * 3 : 48 + (qt - 48) * 4);
  int d = threadIdx.x;                         // 128 threads = one column each
  int q0 = qt * 32;
  for (int row = 0; row < 32; ++row) {
    float m[4], l[4], M = -3.0e38f;
    for (int s = 0; s < nseg; ++s) {
      m[s] = pml[(size_t)(base + s) * 64 + row];
      l[s] = pml[(size_t)(base + s) * 64 + 32 + row];
      M = fmaxf(M, m[s]);
    }
    float L = 0.f, wgt[4];
    for (int s = 0; s < nseg; ++s) { wgt[s] = __expf(m[s] - M); L += l[s] * wgt[s]; }
    float acc = 0.f;
    for (int s = 0; s < nseg; ++s)
      acc += b2f(pO[(size_t)(base + s) * 4096 + row * 128 + d]) * wgt[s];
    yb[(((size_t)(b * T_ + q0 + row)) * H_ + h) * D_ + d] = f2b(acc / L);
  }
}

extern "C" void kernel_launch(void* const* d_in, const int* in_sizes, int n_in,
                              void* d_out, int out_size, void* d_ws, size_t ws_size,
                              hipStream_t stream) {
  (void)in_sizes; (void)n_in; (void)out_size; (void)ws_size;
  const float* x  = (const float*)d_in[0];
  const float* cs = (const float*)d_in[1];
  const float* sn = (const float*)d_in[2];
  const float* Wq = (const float*)d_in[3];
  const float* Wk = (const float*)d_in[4];
  const float* Wv = (const float*)d_in[5];
  const float* Wo = (const float*)d_in[6];
  float* out = (float*)d_out;
  char* ws = (char*)d_ws;

  // workspace layout (bytes); regions reused across phases. total ~88MB.
  unsigned short* xb   = (unsigned short*)(ws + 0);          // 4096x2048 bf16 (dead after qkv)
  unsigned short* Wqt  = (unsigned short*)(ws + 16777216);   // (dead after qkv)
  unsigned short* Wkt  = (unsigned short*)(ws + 25165824);   // (dead after qkv)
  unsigned short* Wvt  = (unsigned short*)(ws + 27262976);   // (dead after qkv)
  unsigned short* Wot  = (unsigned short*)(ws + 29360128);   // needed until out_gemm
  unsigned short* qraw = (unsigned short*)(ws + 37748736);   // (B,T,H,D) bf16
  unsigned short* kraw = (unsigned short*)(ws + 54525952);   // (dead after ropenorm<4>)
  unsigned short* vraw = (unsigned short*)(ws + 58720256);   // (dead after vfrag)
  unsigned short* qfr  = (unsigned short*)(ws + 62914560);   // Q frag order
  unsigned short* kfr  = (unsigned short*)(ws + 79691776);   // K frag order
  unsigned short* vfr  = (unsigned short*)(ws + 83886080);   // V frag order
  unsigned short* yb   = qraw;                               // attention output (B,T,C) bf16
  unsigned short* pO   = (unsigned short*)(ws + 0);          // split-K partials: 3584x8KB
  float*          pml  = (float*)(ws + 54525952);            // split-K (m,l): 3584x256B

  cast_bf16_k<<<dim3(8192), dim3(256), 0, stream>>>(x, xb);
  wtrans<<<dim3(64, 64), dim3(32, 8), 0, stream>>>(Wq, Wqt, 2048, 2048);
  wtrans<<<dim3(16, 64), dim3(32, 8), 0, stream>>>(Wk, Wkt, 2048, 512);
  wtrans<<<dim3(16, 64), dim3(32, 8), 0, stream>>>(Wv, Wvt, 2048, 512);
  wtrans<<<dim3(64, 64), dim3(32, 8), 0, stream>>>(Wo, Wot, 2048, 2048);
  qkv_gemm<<<dim3(24, 32), dim3(256), 0, stream>>>(xb, Wqt, Wkt, Wvt, qraw, kraw, vraw);
  ropenorm<16><<<dim3(16384), dim3(256), 0, stream>>>(qraw, cs, sn, qfr, 0.08838834764831845f);
  ropenorm<4><<<dim3(4096),  dim3(256), 0, stream>>>(kraw, cs, sn, kfr, 1.0f);
  vfrag_k<<<dim3(32, 8), dim3(128, 2), 0, stream>>>(vraw, vfr);
  attn_kernel<<<dim3(144, 32), dim3(64), 0, stream>>>(qfr, kfr, vfr, yb, pO, pml);
  attn_merge<<<dim3(1024), dim3(128), 0, stream>>>(pO, pml, yb);
  out_gemm<<<dim3(16, 32), dim3(256), 0, stream>>>(yb, Wot, out);
}

// Round 6
// 333.596 us; speedup vs baseline: 1.4586x; 1.4586x over previous
//
#include <hip/hip_runtime.h>

using bf16x8 = __attribute__((ext_vector_type(8))) short;
using f32x4  = __attribute__((ext_vector_type(4))) float;

#define B_  2
#define T_  2048
#define C_  2048
#define H_  16
#define KV_ 4
#define D_  128

__device__ __forceinline__ unsigned short f2b(float f) {
  union { float f; unsigned int u; } v; v.f = f;
  unsigned int r = v.u + 0x7fffu + ((v.u >> 16) & 1u);   // RTNE
  return (unsigned short)(r >> 16);
}
__device__ __forceinline__ float b2f(unsigned short u) {
  union { unsigned int u; float f; } v; v.u = ((unsigned int)u) << 16;
  return v.f;
}
// async global->LDS, 16B per lane; LDS dest must be lane-contiguous (wave base + lane*16)
__device__ __forceinline__ void gld_lds16(const void* g, void* l) {
  __builtin_amdgcn_global_load_lds(
      (__attribute__((address_space(1))) void*)g,
      (__attribute__((address_space(3))) void*)l, 16, 0, 0);
}

// ---------------- elementwise cast x -> bf16 ----------------
__global__ void cast_bf16_k(const float* __restrict__ in, unsigned short* __restrict__ out) {
  int i = blockIdx.x * 256 + threadIdx.x;
  float4 f = ((const float4*)in)[i];
  ushort4 u; u.x = f2b(f.x); u.y = f2b(f.y); u.z = f2b(f.z); u.w = f2b(f.w);
  ((ushort4*)out)[i] = u;
}

// ---------------- transpose-cast W (K x N fp32) -> Wt (N x K bf16) ----------------
__global__ void wtrans(const float* __restrict__ W, unsigned short* __restrict__ Wt,
                       int K, int N) {
  __shared__ float s[32][33];
  int n0 = blockIdx.x * 32, k0 = blockIdx.y * 32;
  int tx = threadIdx.x, ty = threadIdx.y;
  #pragma unroll
  for (int yy = 0; yy < 32; yy += 8)
    s[ty + yy][tx] = W[(size_t)(k0 + ty + yy) * N + n0 + tx];
  __syncthreads();
  #pragma unroll
  for (int yy = 0; yy < 32; yy += 8)
    Wt[(size_t)(n0 + ty + yy) * K + k0 + tx] = f2b(s[tx][ty + yy]);
}

// ---------------- m97-style bf16 MFMA GEMM tile: C = A(MxK) * Bt(NxK)^T ----------------
template <bool OUT_BF16>
__device__ __forceinline__ void gemm_tile(
    const unsigned short* __restrict__ A, const unsigned short* __restrict__ Bt,
    void* __restrict__ Cv, int K, int ldc, int m0, int n0b, int n0c,
    unsigned short* sA, unsigned short* sB)
{
  const int tid  = threadIdx.x;
  const int lane = tid & 63, w = tid >> 6;
  const int quad = lane >> 4, l16 = lane & 15;
  const int wm = (w >> 1) * 64, wn = (w & 1) * 64;

  f32x4 acc[4][4] = {};

  const unsigned short* Abase = A  + (size_t)m0  * K;
  const unsigned short* Bbase = Bt + (size_t)n0b * K;

  for (int k0 = 0; k0 < K; k0 += 32) {
    #pragma unroll
    for (int r = 0; r < 2; ++r) {                   // 128x32 bf16 tile = 512 chunks of 16B
      int c = tid + r * 256;
      int row = c >> 2, col = (c & 3) * 8;
      gld_lds16(Abase + (size_t)row * K + k0 + col, sA + c * 8);
      gld_lds16(Bbase + (size_t)row * K + k0 + col, sB + c * 8);
    }
    __syncthreads();                                // drains vmcnt, LDS visible
    bf16x8 af[4], bfr[4];
    #pragma unroll
    for (int i = 0; i < 4; ++i)
      af[i]  = *(const bf16x8*)(sA + (wm + i * 16 + l16) * 32 + quad * 8);
    #pragma unroll
    for (int j = 0; j < 4; ++j)
      bfr[j] = *(const bf16x8*)(sB + (wn + j * 16 + l16) * 32 + quad * 8);
    #pragma unroll
    for (int i = 0; i < 4; ++i)
      #pragma unroll
      for (int j = 0; j < 4; ++j)
        acc[i][j] = __builtin_amdgcn_mfma_f32_16x16x32_bf16(af[i], bfr[j], acc[i][j], 0, 0, 0);
    __syncthreads();                                // all waves done reading before overwrite
  }
  #pragma unroll
  for (int i = 0; i < 4; ++i) {
    #pragma unroll
    for (int r = 0; r < 4; ++r) {
      int row = m0 + wm + i * 16 + quad * 4 + r;    // C/D: row = quad*4+reg, col = lane&15
      #pragma unroll
      for (int j = 0; j < 4; ++j) {
        int col = n0c + wn + j * 16 + l16;
        float v = acc[i][j][r];
        if (OUT_BF16) ((unsigned short*)Cv)[(size_t)row * ldc + col] = f2b(v);
        else          ((float*)Cv)[(size_t)row * ldc + col] = v;
      }
    }
  }
}

// fused QKV projection: 24 n-tiles (16 Q, 4 K, 4 V) x 32 m-tiles
__global__ void qkv_gemm(const unsigned short* __restrict__ xb,
                         const unsigned short* __restrict__ Wqt,
                         const unsigned short* __restrict__ Wkt,
                         const unsigned short* __restrict__ Wvt,
                         unsigned short* q, unsigned short* k, unsigned short* v) {
  __shared__ unsigned short sA[128 * 32], sB[128 * 32];
  int nt = blockIdx.x, mt = blockIdx.y;
  const unsigned short* Bt; unsigned short* C; int n0, ldc;
  if (nt < 16)      { Bt = Wqt; C = q; n0 = nt * 128;        ldc = H_ * D_;  }
  else if (nt < 20) { Bt = Wkt; C = k; n0 = (nt - 16) * 128; ldc = KV_ * D_; }
  else              { Bt = Wvt; C = v; n0 = (nt - 20) * 128; ldc = KV_ * D_; }
  gemm_tile<true>(xb, Bt, C, C_, ldc, mt * 128, n0, n0, sA, sB);
}

__global__ void out_gemm(const unsigned short* __restrict__ yb,
                         const unsigned short* __restrict__ Wot,
                         float* __restrict__ out) {
  __shared__ unsigned short sA[128 * 32], sB[128 * 32];
  gemm_tile<false>(yb, Wot, out, C_, C_, blockIdx.y * 128, blockIdx.x * 128, blockIdx.x * 128,
                   sA, sB);
}

// ---------------- RoPE + RMSNorm -> MFMA-fragment-order output ----------------
// per (b,head): [t16 (128 tiles)][f = d>>3 (16)][t&15 (16)][d&7 (8)]  (tile = 2048 shorts)
template <int NH>
__global__ void ropenorm(const unsigned short* __restrict__ in,
                         const float* __restrict__ cs, const float* __restrict__ sn,
                         unsigned short* __restrict__ out, float oscale) {
  int row  = blockIdx.x * 4 + (threadIdx.x >> 6);
  int lane = threadIdx.x & 63;
  int head = row % NH;
  int t = (row / NH) & (T_ - 1);
  int b = row / (NH * T_);
  const unsigned short* p = in + (size_t)row * D_;
  float t1 = b2f(p[lane]), t2 = b2f(p[lane + 64]);
  float c = cs[t * 64 + lane], s = sn[t * 64 + lane];
  float o1 = t1 * c + t2 * s;
  float o2 = t2 * c - t1 * s;
  float ss = o1 * o1 + o2 * o2;
  #pragma unroll
  for (int off = 32; off > 0; off >>= 1) ss += __shfl_xor(ss, off, 64);
  float r = rsqrtf(ss * (1.0f / 128.0f) + 1.1920929e-07f) * oscale;
  size_t base = ((size_t)((b * NH + head) * 128 + (t >> 4))) * 2048 + (size_t)(t & 15) * 8;
  out[base + (size_t)(lane >> 3) * 128 + (lane & 7)]       = f2b(o1 * r);
  out[base + (size_t)(8 + (lane >> 3)) * 128 + (lane & 7)] = f2b(o2 * r);
}

// ---------------- V repack: (B,T,KV,D) bf16 -> fragment order for PV B-operand ---------
// per (b,kv): [it (32 tiles of 64 t)][dt = d>>4 (8)][f = (t&63)>>3 (8)][d&15 (16)][t&7 (8)]
__global__ void vfrag_k(const unsigned short* __restrict__ v, unsigned short* __restrict__ vf) {
  int it = blockIdx.x;
  int b = blockIdx.y >> 2, kv = blockIdx.y & 3;
  int d = threadIdx.x, ty = threadIdx.y;
  int t0 = it * 64;
  size_t obase = ((size_t)((b * KV_ + kv) * 32 + it)) * 8192
               + (size_t)(d >> 4) * 1024 + (size_t)(d & 15) * 8;
  #pragma unroll
  for (int tcg = 0; tcg < 4; ++tcg) {
    int tc = ty * 4 + tcg;                   // f chunk 0..7
    unsigned short val[8];
    #pragma unroll
    for (int e = 0; e < 8; ++e)              // coalesced: 128 lanes contiguous in d
      val[e] = v[(((size_t)(b * T_) + t0 + tc * 8 + e) * KV_ + kv) * D_ + d];
    ushort4 u0 = {val[0], val[1], val[2], val[3]};
    ushort4 u1 = {val[4], val[5], val[6], val[7]};
    *(ushort4*)(vf + obase + (size_t)tc * 128)     = u0;
    *(ushort4*)(vf + obase + (size_t)tc * 128 + 4) = u1;
  }
}

// ---------------- flash attention v6: static-max softmax, no cross-lane ops in loop ----
// Scores are provably bounded: ||q||2 = 1 (rmsnorm + folded 1/sqrt(D)), ||k||2 = sqrt(128)
// => |s| <= 11.4. Static max M=12 removes max-tracking, alpha-rescale and ALL per-iter
// shuffles; l kept as per-lane partials, reduced once at the end.
// Block = 4 barrier-free waves (qt pair {j,63-j} x 2 heads): identical work per block.
// grid(8,64): linearId%8 = b*4+kv -> each (b,kv)'s K/V stays on one XCD's L2.
__global__ __launch_bounds__(256, 2) void attn_kernel(
    const unsigned short* __restrict__ qf, const unsigned short* __restrict__ kf,
    const unsigned short* __restrict__ vf, unsigned short* __restrict__ yb) {
  __shared__ unsigned short sP[4 * 32 * 72];   // per-wave 32x64 P slice (stride 72)

  const int xp = (int)blockIdx.x;              // 0..7 = b*4+kv  (XCD swizzle)
  const int b = xp >> 2, kv = xp & 3;
  const int yp = (int)blockIdx.y;              // 0..63
  const int j = yp >> 1, hh = yp & 1;
  const int tid = threadIdx.x;
  const int w = tid >> 6, lane = tid & 63;
  const int quad = lane >> 4, l16 = lane & 15;
  const int qt = (w & 1) ? (63 - j) : j;       // paired lengths: block total constant
  const int h = kv * 4 + hh * 2 + (w >> 1);
  const int q0 = qt * 32;
  const int ntile = (qt >> 1) + 1;
  unsigned short* myP = sP + w * (32 * 72);

  const unsigned short* Qf = qf + ((size_t)(b * H_ + h) * 128 + qt * 2) * 2048;
  const unsigned short* Kf = kf + (size_t)(b * KV_ + kv) * 128 * 2048;
  const unsigned short* Vf = vf + (size_t)(b * KV_ + kv) * 32 * 8192;

  // persistent Q fragments (B-operand: n = q row, k = head dim), frag-order (coalesced)
  bf16x8 bq[2][4];
  #pragma unroll
  for (int i = 0; i < 2; ++i)
    #pragma unroll
    for (int kk = 0; kk < 4; ++kk)
      bq[i][kk] = *(const bf16x8*)(Qf + (size_t)i * 2048 + (kk * 4 + quad) * 128 + l16 * 8);

  float l_i[2] = {0.f, 0.f};                   // per-lane partial sum (q = l16 within tile i)
  f32x4 o[2][8] = {};                          // rows q (C-layout), cols d

  for (int it = 0; it < ntile; ++it) {
    const int t0 = it * 64;
    const unsigned short* Kt = Kf + (size_t)(it * 4) * 2048;
    const unsigned short* Vt = Vf + (size_t)it * 8192;

    // S^T = K Q^T : 64 k rows (4 tiles) x 32 q cols (2 tiles)
    f32x4 sc[4][2] = {};
    #pragma unroll
    for (int kk = 0; kk < 4; ++kk) {
      bf16x8 ak[4];
      #pragma unroll
      for (int jt = 0; jt < 4; ++jt)
        ak[jt] = *(const bf16x8*)(Kt + (size_t)jt * 2048 + (kk * 4 + quad) * 128 + l16 * 8);
      #pragma unroll
      for (int jt = 0; jt < 4; ++jt)
        #pragma unroll
        for (int i = 0; i < 2; ++i)
          sc[jt][i] = __builtin_amdgcn_mfma_f32_16x16x32_bf16(ak[jt], bq[i][kk], sc[jt][i], 0, 0, 0);
    }

    // V fragment loads issued here: latency overlaps the softmax below
    bf16x8 bv[2][8];
    #pragma unroll
    for (int kk2 = 0; kk2 < 2; ++kk2)
      #pragma unroll
      for (int jj = 0; jj < 8; ++jj)
        bv[kk2][jj] = *(const bf16x8*)(Vt + (size_t)jj * 1024 + (kk2 * 4 + quad) * 128 + l16 * 8);

    if (it == ntile - 1) {                     // causal mask only on the diagonal tile
      #pragma unroll
      for (int jt = 0; jt < 4; ++jt) {
        int kg = t0 + jt * 16 + quad * 4;
        #pragma unroll
        for (int i = 0; i < 2; ++i) {
          int qg = q0 + i * 16 + l16;
          #pragma unroll
          for (int r = 0; r < 4; ++r)
            if (kg + r > qg) sc[jt][i][r] = -3.0e38f;   // exp -> 0
        }
      }
    }

    // static-max softmax: p = exp(s - 12); per-lane l partials; NO cross-lane ops
    #pragma unroll
    for (int i = 0; i < 2; ++i) {
      float part = 0.f;
      #pragma unroll
      for (int jt = 0; jt < 4; ++jt)
        #pragma unroll
        for (int r = 0; r < 4; ++r) {
          float p = __expf(sc[jt][i][r] - 12.0f);
          sc[jt][i][r] = p; part += p;
        }
      l_i[i] += part;
    }

    // P^T (C-layout) -> private LDS row-major P [q32][k64]
    #pragma unroll
    for (int i = 0; i < 2; ++i)
      #pragma unroll
      for (int jt = 0; jt < 4; ++jt) {
        ushort4 u;
        u.x = f2b(sc[jt][i][0]); u.y = f2b(sc[jt][i][1]);
        u.z = f2b(sc[jt][i][2]); u.w = f2b(sc[jt][i][3]);
        *(ushort4*)(myP + (i * 16 + l16) * 72 + jt * 16 + quad * 4) = u;
      }

    // O += P V : A from private LDS (in-wave ordering, no barrier), B preloaded above
    #pragma unroll
    for (int kk2 = 0; kk2 < 2; ++kk2) {
      bf16x8 ap[2];
      #pragma unroll
      for (int i = 0; i < 2; ++i)
        ap[i] = *(const bf16x8*)(myP + (i * 16 + l16) * 72 + kk2 * 32 + quad * 8);
      #pragma unroll
      for (int i = 0; i < 2; ++i)
        #pragma unroll
        for (int jj = 0; jj < 8; ++jj)
          o[i][jj] = __builtin_amdgcn_mfma_f32_16x16x32_bf16(ap[i], bv[kk2][jj], o[i][jj], 0, 0, 0);
    }
  }

  // final: reduce l across quads (2 shuffles, once), normalize, store
  #pragma unroll
  for (int i = 0; i < 2; ++i) {
    float l = l_i[i];
    l += __shfl_xor(l, 16, 64);
    l += __shfl_xor(l, 32, 64);
    float linv = 1.0f / l;
    float lr[4];
    #pragma unroll
    for (int r = 0; r < 4; ++r) lr[r] = __shfl(linv, quad * 4 + r, 64);
    #pragma unroll
    for (int r = 0; r < 4; ++r) {
      int tg = q0 + i * 16 + quad * 4 + r;
      unsigned short* yr = yb + (((size_t)(b * T_ + tg)) * H_ + h) * D_;
      #pragma unroll
      for (int jj = 0; jj < 8; ++jj)
        yr[jj * 16 + l16] = f2b(o[i][jj][r] * lr[r]);
    }
  }
}

extern "C" void kernel_launch(void* const* d_in, const int* in_sizes, int n_in,
                              void* d_out, int out_size, void* d_ws, size_t ws_size,
                              hipStream_t stream) {
  (void)in_sizes; (void)n_in; (void)out_size; (void)ws_size;
  const float* x  = (const float*)d_in[0];
  const float* cs = (const float*)d_in[1];
  const float* sn = (const float*)d_in[2];
  const float* Wq = (const float*)d_in[3];
  const float* Wk = (const float*)d_in[4];
  const float* Wv = (const float*)d_in[5];
  const float* Wo = (const float*)d_in[6];
  float* out = (float*)d_out;
  char* ws = (char*)d_ws;

  // workspace layout (bytes); regions reused across phases. total ~88MB.
  unsigned short* xb   = (unsigned short*)(ws + 0);          // 4096x2048 bf16 (dead after qkv)
  unsigned short* Wqt  = (unsigned short*)(ws + 16777216);   // (dead after qkv)
  unsigned short* Wkt  = (unsigned short*)(ws + 25165824);   // (dead after qkv)
  unsigned short* Wvt  = (unsigned short*)(ws + 27262976);   // (dead after qkv)
  unsigned short* Wot  = (unsigned short*)(ws + 29360128);   // needed until out_gemm
  unsigned short* qraw = (unsigned short*)(ws + 37748736);   // (B,T,H,D) bf16
  unsigned short* kraw = (unsigned short*)(ws + 54525952);   // (dead after ropenorm<4>)
  unsigned short* vraw = (unsigned short*)(ws + 58720256);   // (dead after vfrag)
  unsigned short* qfr  = (unsigned short*)(ws + 62914560);   // Q frag order
  unsigned short* kfr  = (unsigned short*)(ws + 79691776);   // K frag order
  unsigned short* vfr  = (unsigned short*)(ws + 83886080);   // V frag order
  unsigned short* yb   = qraw;                               // attention output (B,T,C) bf16

  cast_bf16_k<<<dim3(8192), dim3(256), 0, stream>>>(x, xb);
  wtrans<<<dim3(64, 64), dim3(32, 8), 0, stream>>>(Wq, Wqt, 2048, 2048);
  wtrans<<<dim3(16, 64), dim3(32, 8), 0, stream>>>(Wk, Wkt, 2048, 512);
  wtrans<<<dim3(16, 64), dim3(32, 8), 0, stream>>>(Wv, Wvt, 2048, 512);
  wtrans<<<dim3(64, 64), dim3(32, 8), 0, stream>>>(Wo, Wot, 2048, 2048);
  qkv_gemm<<<dim3(24, 32), dim3(256), 0, stream>>>(xb, Wqt, Wkt, Wvt, qraw, kraw, vraw);
  ropenorm<16><<<dim3(16384), dim3(256), 0, stream>>>(qraw, cs, sn, qfr, 0.08838834764831845f);
  ropenorm<4><<<dim3(4096),  dim3(256), 0, stream>>>(kraw, cs, sn, kfr, 1.0f);
  vfrag_k<<<dim3(32, 8), dim3(128, 2), 0, stream>>>(vraw, vfr);
  attn_kernel<<<dim3(8, 64), dim3(256), 0, stream>>>(qfr, kfr, vfr, yb);
  out_gemm<<<dim3(16, 32), dim3(256), 0, stream>>>(yb, Wot, out);
}